// Round 2
// baseline (801.482 us; speedup 1.0000x reference)
//
#include <hip/hip_runtime.h>

// MsgPassingNN: 3 rounds of edge-MLP + segment_sum + node-MLP.
// N=100000 nodes (D=16), E=3200000 edges.
// fe: 32 -> 9 (relu) -> 9 (relu) -> 9 ; fx: 25 -> 9 (relu) -> 9 (relu) -> 16
//
// R4 structure (vs R3):
//   * Per-node counting sort replaced by BUCKET sort (bucket = dst>>7, 128
//     nodes, 782 bins) done in ONE pass: per-block LDS histogram ranks +
//     one global atomic per (block,bin) to reserve a range inside a
//     fixed-slack sed layout (8192 u32 slots per bucket; Poisson(4096)
//     occupancy, overflow probability ~0). Kills hist_k/scan/scatter_k
//     (~280 us, 6.4M global atomics -> ~0.6M).
//   * sed entries are u32: (d_local:7b << 17) | src:17b  (NN < 2^17).
//   * Edge kernel: one block per bucket. base1[bucket] staged in LDS
//     (stride 12, float4-readable), messages accumulated into LDS m[128][9]
//     via ds float atomics (order-arbitrary sum, same class as before),
//     flushed with plain coalesced stores. No wave scan, no global atomics,
//     no m zeroing anywhere.
//   * Layer-1 of fe stays fully hoisted per node (base1 = W1d^T x + b1,
//     base_s = W1s^T x; edge does 9 adds + 2x 9x9 MLP layers).
//   * Final node round writes `out` in place (thread reads only its own row
//     before writing it) -> final D2D memcpy removed.

constexpr int NN = 100000;
constexpr int NE = 3200000;
constexpr int NBK = (NN + 127) / 128;      // 782 buckets of 128 nodes
constexpr int SLOT = 8192;                 // sed slots per bucket (avg fill 4096)
constexpr int EPB = 4096;                  // edges per bsort block (16/thread)
constexpr int NBLK_SORT = (NE + EPB - 1) / EPB;   // 782
constexpr int NB_NODE = (NN + 255) / 256;  // 391

// ---------------- bucket cursor init ----------------

__global__ __launch_bounds__(256) void init_k(int* __restrict__ gcursor)
{
    int i = blockIdx.x * 256 + threadIdx.x;
    if (i < NBK) gcursor[i] = i * SLOT;
}

// ---------------- one-pass bucket sort ----------------

__global__ __launch_bounds__(256) void bsort_k(const int* __restrict__ src,
                                               const int* __restrict__ dst,
                                               int* __restrict__ gcursor,
                                               unsigned* __restrict__ sed)
{
    __shared__ int lhist[NBK];
    __shared__ int lbase[NBK];
    const int t = threadIdx.x;
    for (int i = t; i < NBK; i += 256) lhist[i] = 0;
    __syncthreads();

    const int blkbase = blockIdx.x * EPB;
    unsigned pr[16], sv[16];
    #pragma unroll
    for (int k = 0; k < 16; ++k) {
        const int e = blkbase + k * 256 + t;
        if (e < NE) {
            const int d = dst[e];
            const int s = src[e];
            const int bin = d >> 7;
            const int r = atomicAdd(&lhist[bin], 1);      // LDS atomic
            pr[k] = ((unsigned)bin << 13) | (unsigned)r;  // r < 4096 < 2^13
            sv[k] = ((unsigned)(d & 127) << 17) | (unsigned)s;
        } else {
            pr[k] = 0xFFFFFFFFu;
        }
    }
    __syncthreads();

    for (int i = t; i < NBK; i += 256) {
        const int c = lhist[i];
        if (c) lbase[i] = atomicAdd(&gcursor[i], c);      // one global atomic per (block,bin)
    }
    __syncthreads();

    #pragma unroll
    for (int k = 0; k < 16; ++k) {
        if (pr[k] != 0xFFFFFFFFu) {
            const int bin = (int)(pr[k] >> 13);
            const int r = (int)(pr[k] & 0x1FFFu);
            sed[lbase[bin] + r] = sv[k];
        }
    }
}

// ---------------- round-0 prologue: base1 + base_s from X0 ----------------

__global__ __launch_bounds__(256) void base_k(const float* __restrict__ X,
                                              const float* __restrict__ feW1,
                                              const float* __restrict__ feb1,
                                              float* __restrict__ base1,
                                              float* __restrict__ bases)
{
    __shared__ float sW[32 * 12], sb[9];
    const int t = threadIdx.x;
    for (int i = t; i < 288; i += 256) sW[(i / 9) * 12 + (i % 9)] = feW1[i];
    if (t < 9) sb[t] = feb1[t];
    __syncthreads();

    const int n = blockIdx.x * 256 + t;
    if (n >= NN) return;

    float x[16];
    const float4* p = reinterpret_cast<const float4*>(X + (size_t)n * 16);
    #pragma unroll
    for (int q = 0; q < 4; ++q) {
        float4 v = p[q];
        x[4*q] = v.x; x[4*q+1] = v.y; x[4*q+2] = v.z; x[4*q+3] = v.w;
    }
    float bd[9];
    #pragma unroll
    for (int j = 0; j < 9; ++j) bd[j] = sb[j];
    #pragma unroll
    for (int i = 0; i < 16; ++i) {
        const float xi = x[i];
        #pragma unroll
        for (int j = 0; j < 9; ++j) bd[j] = fmaf(xi, sW[i * 12 + j], bd[j]);
    }
    float bs[9];
    #pragma unroll
    for (int j = 0; j < 9; ++j) bs[j] = 0.f;
    #pragma unroll
    for (int i = 0; i < 16; ++i) {
        const float xi = x[i];
        #pragma unroll
        for (int j = 0; j < 9; ++j) bs[j] = fmaf(xi, sW[(16 + i) * 12 + j], bs[j]);
    }
    float* bp = base1 + (size_t)n * 9;
    #pragma unroll
    for (int j = 0; j < 9; ++j) bp[j] = bd[j];
    float* sp = bases + (size_t)n * 16;
    #pragma unroll
    for (int j = 0; j < 9; ++j) sp[j] = bs[j];
}

// ---------------- edge round: 1 block / bucket, LDS accumulation ----------------

__global__ __launch_bounds__(512) void edge3_k(
    const float* __restrict__ base1,
    const float* __restrict__ bases,
    const unsigned* __restrict__ sed,
    const int* __restrict__ gcursor,
    const float* __restrict__ feW2, const float* __restrict__ feb2,
    const float* __restrict__ feW3, const float* __restrict__ feb3,
    float* __restrict__ m)
{
    __shared__ float sW2[9 * 12], sW3[9 * 12], sb2[9], sb3[9];
    __shared__ float b1l[128 * 12];   // stride 12: float4-readable rows
    __shared__ float ml[128 * 9];
    const int t = threadIdx.x;
    const int b = blockIdx.x;

    if (t < 81)  sW2[(t / 9) * 12 + (t % 9)] = feW2[t];
    if (t >= 128 && t < 209) { int i = t - 128; sW3[(i / 9) * 12 + (i % 9)] = feW3[i]; }
    if (t >= 224 && t < 233) sb2[t - 224] = feb2[t - 224];
    if (t >= 240 && t < 249) sb3[t - 240] = feb3[t - 240];

    const int nbase = b * 128;
    const int nn = (NN - nbase < 128) ? (NN - nbase) : 128;
    for (int i = t; i < nn * 9; i += 512)
        b1l[(i / 9) * 12 + (i % 9)] = base1[(size_t)nbase * 9 + i];
    for (int i = t; i < 128 * 9; i += 512) ml[i] = 0.f;
    __syncthreads();

    const int eend = gcursor[b];
    for (int e = b * SLOT + t; e < eend; e += 512) {
        const unsigned pk = sed[e];
        const int s = (int)(pk & 0x1FFFFu);
        const int dl = (int)(pk >> 17);

        float a[9];
        {
            const float4* ps = reinterpret_cast<const float4*>(bases + (size_t)s * 16);
            float4 c0 = ps[0], c1 = ps[1];
            const float c8 = bases[(size_t)s * 16 + 8];
            const float4* pb = reinterpret_cast<const float4*>(&b1l[dl * 12]);
            float4 b0 = pb[0], b1 = pb[1];
            const float b8 = b1l[dl * 12 + 8];
            a[0] = b0.x + c0.x; a[1] = b0.y + c0.y; a[2] = b0.z + c0.z; a[3] = b0.w + c0.w;
            a[4] = b1.x + c1.x; a[5] = b1.y + c1.y; a[6] = b1.z + c1.z; a[7] = b1.w + c1.w;
            a[8] = b8 + c8;
        }
        #pragma unroll
        for (int j = 0; j < 9; ++j) a[j] = fmaxf(a[j], 0.f);

        float h2[9];
        #pragma unroll
        for (int j = 0; j < 9; ++j) h2[j] = sb2[j];
        #pragma unroll
        for (int i = 0; i < 9; ++i) {
            const float ai = a[i];
            #pragma unroll
            for (int j = 0; j < 9; ++j) h2[j] = fmaf(ai, sW2[i * 12 + j], h2[j]);
        }
        #pragma unroll
        for (int j = 0; j < 9; ++j) h2[j] = fmaxf(h2[j], 0.f);

        float o[9];
        #pragma unroll
        for (int j = 0; j < 9; ++j) o[j] = sb3[j];
        #pragma unroll
        for (int i = 0; i < 9; ++i) {
            const float hi = h2[i];
            #pragma unroll
            for (int j = 0; j < 9; ++j) o[j] = fmaf(hi, sW3[i * 12 + j], o[j]);
        }

        const int d9 = dl * 9;
        #pragma unroll
        for (int j = 0; j < 9; ++j) atomicAdd(&ml[d9 + j], o[j]);
    }
    __syncthreads();

    for (int i = t; i < nn * 9; i += 512) m[(size_t)nbase * 9 + i] = ml[i];
}

// ---------------- node round: fx MLP + next base1/base_s ----------------

__global__ __launch_bounds__(256) void node2_k(
    const float* __restrict__ Xin, const float* __restrict__ m,
    const float* __restrict__ fxW1, const float* __restrict__ fxb1,
    const float* __restrict__ fxW2, const float* __restrict__ fxb2,
    const float* __restrict__ fxW3, const float* __restrict__ fxb3,
    const float* __restrict__ feW1, const float* __restrict__ feb1,
    float* __restrict__ Xout, float* __restrict__ base1out,
    float* __restrict__ basesout)
{
    __shared__ float sU1[25 * 12], sU2[9 * 12], sU3[9 * 16];
    __shared__ float sW1d[16 * 12], sW1s[16 * 12];
    __shared__ float sNB[34], sEB1[9];
    const int t = threadIdx.x;
    if (t < 225) sU1[(t / 9) * 12 + (t % 9)] = fxW1[t];
    if (t < 81)  sU2[(t / 9) * 12 + (t % 9)] = fxW2[t];
    if (t < 144) sU3[t] = fxW3[t];
    if (t < 144) sW1d[(t / 9) * 12 + (t % 9)] = feW1[t];
    if (t >= 112) { int i = t - 112; sW1s[(i / 9) * 12 + (i % 9)] = feW1[144 + i]; }
    if (t < 9) sNB[t] = fxb1[t];
    if (t >= 32 && t < 41) sNB[9 + (t - 32)] = fxb2[t - 32];
    if (t >= 64 && t < 80) sNB[18 + (t - 64)] = fxb3[t - 64];
    if (t >= 96 && t < 105) sEB1[t - 96] = feb1[t - 96];
    __syncthreads();

    const int n = blockIdx.x * 256 + t;
    if (n >= NN) return;

    float xr[16];
    {
        const float4* p = reinterpret_cast<const float4*>(Xin + (size_t)n * 16);
        #pragma unroll
        for (int q = 0; q < 4; ++q) {
            float4 v = p[q];
            xr[4*q] = v.x; xr[4*q+1] = v.y; xr[4*q+2] = v.z; xr[4*q+3] = v.w;
        }
    }
    float mm[9];
    const float* mp = m + (size_t)n * 9;
    #pragma unroll
    for (int j = 0; j < 9; ++j) mm[j] = mp[j];

    float h1[9];
    #pragma unroll
    for (int j = 0; j < 9; ++j) h1[j] = sNB[j];
    #pragma unroll
    for (int i = 0; i < 16; ++i) {
        const float xi = xr[i];
        #pragma unroll
        for (int j = 0; j < 9; ++j) h1[j] = fmaf(xi, sU1[i * 12 + j], h1[j]);
    }
    #pragma unroll
    for (int i = 0; i < 9; ++i) {
        const float xi = mm[i];
        #pragma unroll
        for (int j = 0; j < 9; ++j) h1[j] = fmaf(xi, sU1[(16 + i) * 12 + j], h1[j]);
    }
    #pragma unroll
    for (int j = 0; j < 9; ++j) h1[j] = fmaxf(h1[j], 0.f);

    float h2[9];
    #pragma unroll
    for (int j = 0; j < 9; ++j) h2[j] = sNB[9 + j];
    #pragma unroll
    for (int i = 0; i < 9; ++i) {
        const float xi = h1[i];
        #pragma unroll
        for (int j = 0; j < 9; ++j) h2[j] = fmaf(xi, sU2[i * 12 + j], h2[j]);
    }
    #pragma unroll
    for (int j = 0; j < 9; ++j) h2[j] = fmaxf(h2[j], 0.f);

    float o[16];
    #pragma unroll
    for (int k = 0; k < 16; ++k) o[k] = sNB[18 + k];
    #pragma unroll
    for (int j = 0; j < 9; ++j) {
        const float hj = h2[j];
        #pragma unroll
        for (int k = 0; k < 16; ++k) o[k] = fmaf(hj, sU3[j * 16 + k], o[k]);
    }

    float4* po = reinterpret_cast<float4*>(Xout + (size_t)n * 16);
    #pragma unroll
    for (int q = 0; q < 4; ++q) {
        float4 v;
        v.x = o[4*q]; v.y = o[4*q+1]; v.z = o[4*q+2]; v.w = o[4*q+3];
        po[q] = v;
    }

    // base1 / base_s for NEXT round's edge kernel
    float bb[9];
    #pragma unroll
    for (int j = 0; j < 9; ++j) bb[j] = sEB1[j];
    #pragma unroll
    for (int i = 0; i < 16; ++i) {
        const float xi = o[i];
        #pragma unroll
        for (int j = 0; j < 9; ++j) bb[j] = fmaf(xi, sW1d[i * 12 + j], bb[j]);
    }
    float* bp = base1out + (size_t)n * 9;
    #pragma unroll
    for (int j = 0; j < 9; ++j) bp[j] = bb[j];

    float cc[9];
    #pragma unroll
    for (int j = 0; j < 9; ++j) cc[j] = 0.f;
    #pragma unroll
    for (int i = 0; i < 16; ++i) {
        const float xi = o[i];
        #pragma unroll
        for (int j = 0; j < 9; ++j) cc[j] = fmaf(xi, sW1s[i * 12 + j], cc[j]);
    }
    float* sp = basesout + (size_t)n * 16;
    #pragma unroll
    for (int j = 0; j < 9; ++j) sp[j] = cc[j];
}

extern "C" void kernel_launch(void* const* d_in, const int* in_sizes, int n_in,
                              void* d_out, int out_size, void* d_ws, size_t ws_size,
                              hipStream_t stream)
{
    (void)in_sizes; (void)n_in; (void)out_size; (void)ws_size;
    const float* X0   = (const float*)d_in[0];
    const int*   esrc = (const int*)d_in[1];
    const int*   edst = (const int*)d_in[2];
    const float* feW1 = (const float*)d_in[3];
    const float* feb1 = (const float*)d_in[4];
    const float* feW2 = (const float*)d_in[5];
    const float* feb2 = (const float*)d_in[6];
    const float* feW3 = (const float*)d_in[7];
    const float* feb3 = (const float*)d_in[8];
    const float* fxW1 = (const float*)d_in[9];
    const float* fxb1 = (const float*)d_in[10];
    const float* fxW2 = (const float*)d_in[11];
    const float* fxb2 = (const float*)d_in[12];
    const float* fxW3 = (const float*)d_in[13];
    const float* fxb3 = (const float*)d_in[14];
    float* out = (float*)d_out;

    // workspace layout (floats unless noted); everything rebuilt each launch.
    float* Xa     = (float*)d_ws;                       // NN*16
    float* base1  = Xa + (size_t)NN * 16;               // NN*9
    float* bases  = base1 + (size_t)NN * 9;             // NN*16 (64B rows; offset 16B-aligned)
    float* mb     = bases + (size_t)NN * 16;            // NN*9
    int* gcursor  = (int*)(mb + (size_t)NN * 9);        // NBK (padded to 1024)
    unsigned* sed = (unsigned*)(gcursor + 1024);        // NBK*SLOT u32 = 25.6MB

    const dim3 thr(256);
    const dim3 gS(NBLK_SORT);    // 782
    const dim3 gB(NBK);          // 782
    const dim3 gN(NB_NODE);      // 391

    // ---- bucket sort (once per launch) ----
    init_k<<<4, thr, 0, stream>>>(gcursor);
    bsort_k<<<gS, thr, 0, stream>>>(esrc, edst, gcursor, sed);

    // ---- round 0 ----
    base_k<<<gN, thr, 0, stream>>>(X0, feW1, feb1, base1, bases);
    edge3_k<<<gB, dim3(512), 0, stream>>>(base1, bases, sed, gcursor,
                                          feW2, feb2, feW3, feb3, mb);
    node2_k<<<gN, thr, 0, stream>>>(X0, mb, fxW1, fxb1, fxW2, fxb2, fxW3, fxb3,
                                    feW1, feb1, Xa, base1, bases);
    // ---- round 1 ----
    edge3_k<<<gB, dim3(512), 0, stream>>>(base1, bases, sed, gcursor,
                                          feW2, feb2, feW3, feb3, mb);
    node2_k<<<gN, thr, 0, stream>>>(Xa, mb, fxW1, fxb1, fxW2, fxb2, fxW3, fxb3,
                                    feW1, feb1, out, base1, bases);
    // ---- round 2 (node writes out in place: each thread touches only row n) ----
    edge3_k<<<gB, dim3(512), 0, stream>>>(base1, bases, sed, gcursor,
                                          feW2, feb2, feW3, feb3, mb);
    node2_k<<<gN, thr, 0, stream>>>(out, mb, fxW1, fxb1, fxW2, fxb2, fxW3, fxb3,
                                    feW1, feb1, out, base1, bases);
}

// Round 3
// 785.146 us; speedup vs baseline: 1.0208x; 1.0208x over previous
//
#include <hip/hip_runtime.h>

// MsgPassingNN: 3 rounds of edge-MLP + segment_sum + node-MLP.
// N=100000 nodes (D=16), E=3200000 edges.
// fe: 32 -> 9 (relu) -> 9 (relu) -> 9 ; fx: 25 -> 9 (relu) -> 9 (relu) -> 16
//
// R5 structure (vs R4):
//   * edge kernel split KSPLIT=4 ways per bucket (3128 blocks of 512, ~1-2
//     loop iters/thread) -> restores TLP that R4 starved (207us latency-bound,
//     occupancy 18%). Each block accumulates a PARTIAL m for its bucket in
//     LDS and flushes with plain coalesced stores to its own partial array;
//     node kernel sums the 4 partials. Zero global atomics in the rounds.
//   * Xa buffer + final D2D memcpy removed: round 0 node writes `out`,
//     rounds 1-2 update `out` in place (each thread reads only its own row
//     before writing it; edge kernels never read X).
//   * Everything else per R4: one-pass bucket sort (bucket = dst>>7, u32
//     sed entries (d_local:7 | src:17), fe layer-1 fully hoisted per node
//     (base1 = W1d^T x + b1, base_s = W1s^T x), edge does 9 adds + 2x 9x9.

constexpr int NN = 100000;
constexpr int NE = 3200000;
constexpr int NBK = (NN + 127) / 128;      // 782 buckets of 128 nodes
constexpr int SLOT = 8192;                 // sed slots per bucket (avg fill 4096)
constexpr int EPB = 4096;                  // edges per bsort block (16/thread)
constexpr int NBLK_SORT = (NE + EPB - 1) / EPB;   // 782
constexpr int NB_NODE = (NN + 255) / 256;  // 391
constexpr int KSPLIT = 4;                  // blocks per bucket in edge round

// ---------------- bucket cursor init ----------------

__global__ __launch_bounds__(256) void init_k(int* __restrict__ gcursor)
{
    int i = blockIdx.x * 256 + threadIdx.x;
    if (i < NBK) gcursor[i] = i * SLOT;
}

// ---------------- one-pass bucket sort ----------------

__global__ __launch_bounds__(256) void bsort_k(const int* __restrict__ src,
                                               const int* __restrict__ dst,
                                               int* __restrict__ gcursor,
                                               unsigned* __restrict__ sed)
{
    __shared__ int lhist[NBK];
    __shared__ int lbase[NBK];
    const int t = threadIdx.x;
    for (int i = t; i < NBK; i += 256) lhist[i] = 0;
    __syncthreads();

    const int blkbase = blockIdx.x * EPB;
    unsigned pr[16], sv[16];
    #pragma unroll
    for (int k = 0; k < 16; ++k) {
        const int e = blkbase + k * 256 + t;
        if (e < NE) {
            const int d = dst[e];
            const int s = src[e];
            const int bin = d >> 7;
            const int r = atomicAdd(&lhist[bin], 1);      // LDS atomic
            pr[k] = ((unsigned)bin << 13) | (unsigned)r;  // r < 4096 < 2^13
            sv[k] = ((unsigned)(d & 127) << 17) | (unsigned)s;
        } else {
            pr[k] = 0xFFFFFFFFu;
        }
    }
    __syncthreads();

    for (int i = t; i < NBK; i += 256) {
        const int c = lhist[i];
        if (c) lbase[i] = atomicAdd(&gcursor[i], c);      // 1 global atomic/(block,bin)
    }
    __syncthreads();

    #pragma unroll
    for (int k = 0; k < 16; ++k) {
        if (pr[k] != 0xFFFFFFFFu) {
            const int bin = (int)(pr[k] >> 13);
            const int r = (int)(pr[k] & 0x1FFFu);
            sed[lbase[bin] + r] = sv[k];
        }
    }
}

// ---------------- round-0 prologue: base1 + base_s from X0 ----------------

__global__ __launch_bounds__(256) void base_k(const float* __restrict__ X,
                                              const float* __restrict__ feW1,
                                              const float* __restrict__ feb1,
                                              float* __restrict__ base1,
                                              float* __restrict__ bases)
{
    __shared__ float sW[32 * 12], sb[9];
    const int t = threadIdx.x;
    for (int i = t; i < 288; i += 256) sW[(i / 9) * 12 + (i % 9)] = feW1[i];
    if (t < 9) sb[t] = feb1[t];
    __syncthreads();

    const int n = blockIdx.x * 256 + t;
    if (n >= NN) return;

    float x[16];
    const float4* p = reinterpret_cast<const float4*>(X + (size_t)n * 16);
    #pragma unroll
    for (int q = 0; q < 4; ++q) {
        float4 v = p[q];
        x[4*q] = v.x; x[4*q+1] = v.y; x[4*q+2] = v.z; x[4*q+3] = v.w;
    }
    float bd[9];
    #pragma unroll
    for (int j = 0; j < 9; ++j) bd[j] = sb[j];
    #pragma unroll
    for (int i = 0; i < 16; ++i) {
        const float xi = x[i];
        #pragma unroll
        for (int j = 0; j < 9; ++j) bd[j] = fmaf(xi, sW[i * 12 + j], bd[j]);
    }
    float bs[9];
    #pragma unroll
    for (int j = 0; j < 9; ++j) bs[j] = 0.f;
    #pragma unroll
    for (int i = 0; i < 16; ++i) {
        const float xi = x[i];
        #pragma unroll
        for (int j = 0; j < 9; ++j) bs[j] = fmaf(xi, sW[(16 + i) * 12 + j], bs[j]);
    }
    float* bp = base1 + (size_t)n * 9;
    #pragma unroll
    for (int j = 0; j < 9; ++j) bp[j] = bd[j];
    float* sp = bases + (size_t)n * 16;
    #pragma unroll
    for (int j = 0; j < 9; ++j) sp[j] = bs[j];
}

// ---------------- edge round: KSPLIT blocks / bucket, LDS partials ----------------

__global__ __launch_bounds__(512) void edge4_k(
    const float* __restrict__ base1,
    const float* __restrict__ bases,
    const unsigned* __restrict__ sed,
    const int* __restrict__ gcursor,
    const float* __restrict__ feW2, const float* __restrict__ feb2,
    const float* __restrict__ feW3, const float* __restrict__ feb3,
    float* __restrict__ mq)   // KSPLIT arrays of NN*9, back to back
{
    __shared__ float sW2[9 * 12], sW3[9 * 12], sb2[9], sb3[9];
    __shared__ float b1l[128 * 12];   // stride 12: float4-readable rows
    __shared__ float ml[128 * 9];
    const int t = threadIdx.x;
    const int bq = blockIdx.x;
    const int b = bq >> 2;            // bucket
    const int q = bq & (KSPLIT - 1);  // which quarter / partial array

    if (t < 81)  sW2[(t / 9) * 12 + (t % 9)] = feW2[t];
    if (t >= 128 && t < 209) { int i = t - 128; sW3[(i / 9) * 12 + (i % 9)] = feW3[i]; }
    if (t >= 224 && t < 233) sb2[t - 224] = feb2[t - 224];
    if (t >= 240 && t < 249) sb3[t - 240] = feb3[t - 240];

    const int nbase = b * 128;
    const int nn = (NN - nbase < 128) ? (NN - nbase) : 128;
    for (int i = t; i < nn * 9; i += 512)
        b1l[(i / 9) * 12 + (i % 9)] = base1[(size_t)nbase * 9 + i];
    for (int i = t; i < 128 * 9; i += 512) ml[i] = 0.f;
    __syncthreads();

    const int eend = gcursor[b];
    const int bstart = b * SLOT;
    for (int cbase = bstart + q * 512; cbase < eend; cbase += KSPLIT * 512) {
        const int e = cbase + t;
        if (e < eend) {
            const unsigned pk = sed[e];
            const int s = (int)(pk & 0x1FFFFu);
            const int dl = (int)(pk >> 17);

            float a[9];
            {
                const float4* ps = reinterpret_cast<const float4*>(bases + (size_t)s * 16);
                float4 c0 = ps[0], c1 = ps[1];
                const float c8 = bases[(size_t)s * 16 + 8];
                const float4* pb = reinterpret_cast<const float4*>(&b1l[dl * 12]);
                float4 b0 = pb[0], b1 = pb[1];
                const float b8 = b1l[dl * 12 + 8];
                a[0] = b0.x + c0.x; a[1] = b0.y + c0.y; a[2] = b0.z + c0.z; a[3] = b0.w + c0.w;
                a[4] = b1.x + c1.x; a[5] = b1.y + c1.y; a[6] = b1.z + c1.z; a[7] = b1.w + c1.w;
                a[8] = b8 + c8;
            }
            #pragma unroll
            for (int j = 0; j < 9; ++j) a[j] = fmaxf(a[j], 0.f);

            float h2[9];
            #pragma unroll
            for (int j = 0; j < 9; ++j) h2[j] = sb2[j];
            #pragma unroll
            for (int i = 0; i < 9; ++i) {
                const float ai = a[i];
                #pragma unroll
                for (int j = 0; j < 9; ++j) h2[j] = fmaf(ai, sW2[i * 12 + j], h2[j]);
            }
            #pragma unroll
            for (int j = 0; j < 9; ++j) h2[j] = fmaxf(h2[j], 0.f);

            float o[9];
            #pragma unroll
            for (int j = 0; j < 9; ++j) o[j] = sb3[j];
            #pragma unroll
            for (int i = 0; i < 9; ++i) {
                const float hi = h2[i];
                #pragma unroll
                for (int j = 0; j < 9; ++j) o[j] = fmaf(hi, sW3[i * 12 + j], o[j]);
            }

            const int d9 = dl * 9;
            #pragma unroll
            for (int j = 0; j < 9; ++j) atomicAdd(&ml[d9 + j], o[j]);
        }
    }
    __syncthreads();

    // coalesced flush of this block's partial into its own array (no atomics)
    float* mp = mq + (size_t)q * NN * 9 + (size_t)nbase * 9;
    for (int i = t; i < nn * 9; i += 512) mp[i] = ml[i];
}

// ---------------- node round: fx MLP (+sum partials) + next base1/base_s ----------------

__global__ __launch_bounds__(256) void node3_k(
    const float* __restrict__ Xin, const float* __restrict__ mq,
    const float* __restrict__ fxW1, const float* __restrict__ fxb1,
    const float* __restrict__ fxW2, const float* __restrict__ fxb2,
    const float* __restrict__ fxW3, const float* __restrict__ fxb3,
    const float* __restrict__ feW1, const float* __restrict__ feb1,
    float* __restrict__ Xout, float* __restrict__ base1out,
    float* __restrict__ basesout)
{
    __shared__ float sU1[25 * 12], sU2[9 * 12], sU3[9 * 16];
    __shared__ float sW1d[16 * 12], sW1s[16 * 12];
    __shared__ float sNB[34], sEB1[9];
    const int t = threadIdx.x;
    if (t < 225) sU1[(t / 9) * 12 + (t % 9)] = fxW1[t];
    if (t < 81)  sU2[(t / 9) * 12 + (t % 9)] = fxW2[t];
    if (t < 144) sU3[t] = fxW3[t];
    if (t < 144) sW1d[(t / 9) * 12 + (t % 9)] = feW1[t];
    if (t >= 112) { int i = t - 112; sW1s[(i / 9) * 12 + (i % 9)] = feW1[144 + i]; }
    if (t < 9) sNB[t] = fxb1[t];
    if (t >= 32 && t < 41) sNB[9 + (t - 32)] = fxb2[t - 32];
    if (t >= 64 && t < 80) sNB[18 + (t - 64)] = fxb3[t - 64];
    if (t >= 96 && t < 105) sEB1[t - 96] = feb1[t - 96];
    __syncthreads();

    const int n = blockIdx.x * 256 + t;
    if (n >= NN) return;

    float xr[16];
    {
        const float4* p = reinterpret_cast<const float4*>(Xin + (size_t)n * 16);
        #pragma unroll
        for (int q = 0; q < 4; ++q) {
            float4 v = p[q];
            xr[4*q] = v.x; xr[4*q+1] = v.y; xr[4*q+2] = v.z; xr[4*q+3] = v.w;
        }
    }
    float mm[9];
    #pragma unroll
    for (int j = 0; j < 9; ++j) mm[j] = mq[(size_t)n * 9 + j];
    #pragma unroll
    for (int qq = 1; qq < KSPLIT; ++qq) {
        const float* mp = mq + (size_t)qq * NN * 9 + (size_t)n * 9;
        #pragma unroll
        for (int j = 0; j < 9; ++j) mm[j] += mp[j];
    }

    float h1[9];
    #pragma unroll
    for (int j = 0; j < 9; ++j) h1[j] = sNB[j];
    #pragma unroll
    for (int i = 0; i < 16; ++i) {
        const float xi = xr[i];
        #pragma unroll
        for (int j = 0; j < 9; ++j) h1[j] = fmaf(xi, sU1[i * 12 + j], h1[j]);
    }
    #pragma unroll
    for (int i = 0; i < 9; ++i) {
        const float xi = mm[i];
        #pragma unroll
        for (int j = 0; j < 9; ++j) h1[j] = fmaf(xi, sU1[(16 + i) * 12 + j], h1[j]);
    }
    #pragma unroll
    for (int j = 0; j < 9; ++j) h1[j] = fmaxf(h1[j], 0.f);

    float h2[9];
    #pragma unroll
    for (int j = 0; j < 9; ++j) h2[j] = sNB[9 + j];
    #pragma unroll
    for (int i = 0; i < 9; ++i) {
        const float xi = h1[i];
        #pragma unroll
        for (int j = 0; j < 9; ++j) h2[j] = fmaf(xi, sU2[i * 12 + j], h2[j]);
    }
    #pragma unroll
    for (int j = 0; j < 9; ++j) h2[j] = fmaxf(h2[j], 0.f);

    float o[16];
    #pragma unroll
    for (int k = 0; k < 16; ++k) o[k] = sNB[18 + k];
    #pragma unroll
    for (int j = 0; j < 9; ++j) {
        const float hj = h2[j];
        #pragma unroll
        for (int k = 0; k < 16; ++k) o[k] = fmaf(hj, sU3[j * 16 + k], o[k]);
    }

    float4* po = reinterpret_cast<float4*>(Xout + (size_t)n * 16);
    #pragma unroll
    for (int q = 0; q < 4; ++q) {
        float4 v;
        v.x = o[4*q]; v.y = o[4*q+1]; v.z = o[4*q+2]; v.w = o[4*q+3];
        po[q] = v;
    }

    // base1 / base_s for NEXT round's edge kernel
    float bb[9];
    #pragma unroll
    for (int j = 0; j < 9; ++j) bb[j] = sEB1[j];
    #pragma unroll
    for (int i = 0; i < 16; ++i) {
        const float xi = o[i];
        #pragma unroll
        for (int j = 0; j < 9; ++j) bb[j] = fmaf(xi, sW1d[i * 12 + j], bb[j]);
    }
    float* bp = base1out + (size_t)n * 9;
    #pragma unroll
    for (int j = 0; j < 9; ++j) bp[j] = bb[j];

    float cc[9];
    #pragma unroll
    for (int j = 0; j < 9; ++j) cc[j] = 0.f;
    #pragma unroll
    for (int i = 0; i < 16; ++i) {
        const float xi = o[i];
        #pragma unroll
        for (int j = 0; j < 9; ++j) cc[j] = fmaf(xi, sW1s[i * 12 + j], cc[j]);
    }
    float* sp = basesout + (size_t)n * 16;
    #pragma unroll
    for (int j = 0; j < 9; ++j) sp[j] = cc[j];
}

extern "C" void kernel_launch(void* const* d_in, const int* in_sizes, int n_in,
                              void* d_out, int out_size, void* d_ws, size_t ws_size,
                              hipStream_t stream)
{
    (void)in_sizes; (void)n_in; (void)out_size; (void)ws_size;
    const float* X0   = (const float*)d_in[0];
    const int*   esrc = (const int*)d_in[1];
    const int*   edst = (const int*)d_in[2];
    const float* feW1 = (const float*)d_in[3];
    const float* feb1 = (const float*)d_in[4];
    const float* feW2 = (const float*)d_in[5];
    const float* feb2 = (const float*)d_in[6];
    const float* feW3 = (const float*)d_in[7];
    const float* feb3 = (const float*)d_in[8];
    const float* fxW1 = (const float*)d_in[9];
    const float* fxb1 = (const float*)d_in[10];
    const float* fxW2 = (const float*)d_in[11];
    const float* fxb2 = (const float*)d_in[12];
    const float* fxW3 = (const float*)d_in[13];
    const float* fxb3 = (const float*)d_in[14];
    float* out = (float*)d_out;

    // workspace layout (floats unless noted). total ~50 MB.
    float* base1  = (float*)d_ws;                       // NN*9
    float* bases  = base1 + (size_t)NN * 9;             // NN*16 (64B rows)
    float* mq     = bases + (size_t)NN * 16;            // KSPLIT * NN*9
    int* gcursor  = (int*)(mq + (size_t)KSPLIT * NN * 9); // NBK (padded to 1024)
    unsigned* sed = (unsigned*)(gcursor + 1024);        // NBK*SLOT u32 = 25.6MB

    const dim3 thr(256);
    const dim3 gS(NBLK_SORT);        // 782
    const dim3 gB(NBK * KSPLIT);     // 3128
    const dim3 gN(NB_NODE);          // 391

    // ---- bucket sort (once per launch) ----
    init_k<<<4, thr, 0, stream>>>(gcursor);
    bsort_k<<<gS, thr, 0, stream>>>(esrc, edst, gcursor, sed);

    // ---- round 0 ----
    base_k<<<gN, thr, 0, stream>>>(X0, feW1, feb1, base1, bases);
    edge4_k<<<gB, dim3(512), 0, stream>>>(base1, bases, sed, gcursor,
                                          feW2, feb2, feW3, feb3, mq);
    node3_k<<<gN, thr, 0, stream>>>(X0, mq, fxW1, fxb1, fxW2, fxb2, fxW3, fxb3,
                                    feW1, feb1, out, base1, bases);
    // ---- round 1 (node updates out in place; edge never reads X) ----
    edge4_k<<<gB, dim3(512), 0, stream>>>(base1, bases, sed, gcursor,
                                          feW2, feb2, feW3, feb3, mq);
    node3_k<<<gN, thr, 0, stream>>>(out, mq, fxW1, fxb1, fxW2, fxb2, fxW3, fxb3,
                                    feW1, feb1, out, base1, bases);
    // ---- round 2 ----
    edge4_k<<<gB, dim3(512), 0, stream>>>(base1, bases, sed, gcursor,
                                          feW2, feb2, feW3, feb3, mq);
    node3_k<<<gN, thr, 0, stream>>>(out, mq, fxW1, fxb1, fxW2, fxb2, fxW3, fxb3,
                                    feW1, feb1, out, base1, bases);
}

// Round 4
// 559.134 us; speedup vs baseline: 1.4334x; 1.4042x over previous
//
#include <hip/hip_runtime.h>

// MsgPassingNN: 3 rounds of edge-MLP + segment_sum + node-MLP.
// N=100000 nodes (D=16), E=3200000 edges.
// fe: 32 -> 9 (relu) -> 9 (relu) -> 9 ; fx: 25 -> 9 (relu) -> 9 (relu) -> 16
//
// R6 structure = proven-fast halves of R3 and R5:
//   * Two-level full dst-sort (replaces R3's 280us CSR build):
//       bsort_k: one pass, bucket = dst>>7 (782 buckets, 8192-slot slack
//                regions), LDS-histogram ranks + 1 global atomic/(block,bin).
//       lsort_k: one block per bucket: load bucket to LDS, 128-bin hist +
//                scan + LDS counting-scatter, coalesced write-back in place.
//     -> sed fully sorted by dst within each bucket (u32: d_local:7 | src:17).
//   * edge5_k = R3's empirically-fast edge kernel (1 thread/edge, 256-thr
//     blocks, ~36 VGPR -> 8 waves/SIMD): grid covers all slack slots, blocks
//     past bucket fill exit immediately; wave-segmented scan (ballot/clz
//     distance-to-head) + segment-tail global atomics (~1.3M).
//   * fe layer-1 fully hoisted per node (base1 = W1d^T x + b1 stride 12,
//     base_s = W1s^T x stride 16/64B rows); edge = 9 adds + relu + 2x 9x9.
//   * node kernel: fx MLP, zeroes m for next round, writes out in place,
//     recomputes base1/base_s.

constexpr int NN = 100000;
constexpr int NE = 3200000;
constexpr int NBK = (NN + 127) / 128;      // 782 buckets of 128 nodes
constexpr int SLOT = 8192;                 // sed slots per bucket (avg fill 4096)
constexpr int EPB = 4096;                  // edges per bsort block (16/thread)
constexpr int NBLK_SORT = (NE + EPB - 1) / EPB;   // 782
constexpr int NB_NODE = (NN + 255) / 256;  // 391

// ---------------- bucket cursor init ----------------

__global__ __launch_bounds__(256) void init_k(int* __restrict__ gcursor)
{
    int i = blockIdx.x * 256 + threadIdx.x;
    if (i < NBK) gcursor[i] = i * SLOT;
}

// ---------------- pass 1: bucket sort (dst>>7) ----------------

__global__ __launch_bounds__(256) void bsort_k(const int* __restrict__ src,
                                               const int* __restrict__ dst,
                                               int* __restrict__ gcursor,
                                               unsigned* __restrict__ sed)
{
    __shared__ int lhist[NBK];
    __shared__ int lbase[NBK];
    const int t = threadIdx.x;
    for (int i = t; i < NBK; i += 256) lhist[i] = 0;
    __syncthreads();

    const int blkbase = blockIdx.x * EPB;
    unsigned pr[16], sv[16];
    #pragma unroll
    for (int k = 0; k < 16; ++k) {
        const int e = blkbase + k * 256 + t;
        if (e < NE) {
            const int d = dst[e];
            const int s = src[e];
            const int bin = d >> 7;
            const int r = atomicAdd(&lhist[bin], 1);      // LDS atomic
            pr[k] = ((unsigned)bin << 13) | (unsigned)r;  // r < 4096 < 2^13
            sv[k] = ((unsigned)(d & 127) << 17) | (unsigned)s;
        } else {
            pr[k] = 0xFFFFFFFFu;
        }
    }
    __syncthreads();

    for (int i = t; i < NBK; i += 256) {
        const int c = lhist[i];
        if (c) lbase[i] = atomicAdd(&gcursor[i], c);      // 1 global atomic/(block,bin)
    }
    __syncthreads();

    #pragma unroll
    for (int k = 0; k < 16; ++k) {
        if (pr[k] != 0xFFFFFFFFu) {
            const int bin = (int)(pr[k] >> 13);
            const int r = (int)(pr[k] & 0x1FFFu);
            sed[lbase[bin] + r] = sv[k];
        }
    }
}

// ---------------- pass 2: in-bucket counting sort by d_local (in place) ----------------

__global__ __launch_bounds__(512) void lsort_k(unsigned* __restrict__ sed,
                                               const int* __restrict__ gcursor)
{
    __shared__ unsigned buf[SLOT];    // 32 KB
    __shared__ unsigned obuf[SLOT];   // 32 KB
    __shared__ int hist[128];
    __shared__ int cur[128];
    const int t = threadIdx.x;
    const int b = blockIdx.x;
    const int base = b * SLOT;
    int fill = gcursor[b] - base;
    if (fill > SLOT) fill = SLOT;     // safety clamp (never hit for this input)

    if (t < 128) hist[t] = 0;
    __syncthreads();
    for (int i = t; i < fill; i += 512) {
        unsigned v = sed[base + i];
        buf[i] = v;
        atomicAdd(&hist[v >> 17], 1);
    }
    __syncthreads();
    // exclusive scan of 128 bins (Hillis-Steele in LDS)
    if (t < 128) cur[t] = hist[t];
    __syncthreads();
    for (int off = 1; off < 128; off <<= 1) {
        int a = (t < 128 && t >= off) ? cur[t - off] : 0;
        __syncthreads();
        if (t < 128) cur[t] += a;
        __syncthreads();
    }
    if (t < 128) cur[t] -= hist[t];   // exclusive prefix
    __syncthreads();
    for (int i = t; i < fill; i += 512) {
        unsigned v = buf[i];
        int r = atomicAdd(&cur[v >> 17], 1);
        obuf[r] = v;
    }
    __syncthreads();
    for (int i = t; i < fill; i += 512) sed[base + i] = obuf[i];
}

// ---------------- round-0 prologue: base1 + base_s from X0, zero m ----------------

__global__ __launch_bounds__(256) void base_k(const float* __restrict__ X,
                                              const float* __restrict__ feW1,
                                              const float* __restrict__ feb1,
                                              float* __restrict__ base1,
                                              float* __restrict__ bases,
                                              float* __restrict__ m)
{
    __shared__ float sW[32 * 12], sb[9];
    const int t = threadIdx.x;
    for (int i = t; i < 288; i += 256) sW[(i / 9) * 12 + (i % 9)] = feW1[i];
    if (t < 9) sb[t] = feb1[t];
    __syncthreads();

    const int n = blockIdx.x * 256 + t;
    if (n >= NN) return;

    float x[16];
    const float4* p = reinterpret_cast<const float4*>(X + (size_t)n * 16);
    #pragma unroll
    for (int q = 0; q < 4; ++q) {
        float4 v = p[q];
        x[4*q] = v.x; x[4*q+1] = v.y; x[4*q+2] = v.z; x[4*q+3] = v.w;
    }
    float bd[9];
    #pragma unroll
    for (int j = 0; j < 9; ++j) bd[j] = sb[j];
    #pragma unroll
    for (int i = 0; i < 16; ++i) {
        const float xi = x[i];
        #pragma unroll
        for (int j = 0; j < 9; ++j) bd[j] = fmaf(xi, sW[i * 12 + j], bd[j]);
    }
    float bs[9];
    #pragma unroll
    for (int j = 0; j < 9; ++j) bs[j] = 0.f;
    #pragma unroll
    for (int i = 0; i < 16; ++i) {
        const float xi = x[i];
        #pragma unroll
        for (int j = 0; j < 9; ++j) bs[j] = fmaf(xi, sW[(16 + i) * 12 + j], bs[j]);
    }
    float* bp = base1 + (size_t)n * 12;
    #pragma unroll
    for (int j = 0; j < 9; ++j) bp[j] = bd[j];
    float* sp = bases + (size_t)n * 16;
    #pragma unroll
    for (int j = 0; j < 9; ++j) sp[j] = bs[j];
    float* mp = m + (size_t)n * 9;
    #pragma unroll
    for (int j = 0; j < 9; ++j) mp[j] = 0.f;
}

// ---------------- edge round: 1 thread / sorted slot, wave scan ----------------

__global__ __launch_bounds__(256) void edge5_k(
    const float* __restrict__ base1,
    const float* __restrict__ bases,
    const unsigned* __restrict__ sed,
    const int* __restrict__ gcursor,
    const float* __restrict__ feW2, const float* __restrict__ feb2,
    const float* __restrict__ feW3, const float* __restrict__ feb3,
    float* __restrict__ m)
{
    const int t = threadIdx.x;
    const int b = blockIdx.x >> 5;                 // bucket (SLOT/256 = 32 blocks/bucket)
    const int idx0 = (blockIdx.x & 31) * 256;      // slot offset within bucket
    const int fill = gcursor[b] - b * SLOT;
    if (idx0 >= fill) return;                      // block-uniform early exit

    __shared__ float sW2[9 * 12], sW3[9 * 12], sb2[9], sb3[9];
    if (t < 81)  sW2[(t / 9) * 12 + (t % 9)] = feW2[t];
    if (t >= 128 && t < 209) { int i = t - 128; sW3[(i / 9) * 12 + (i % 9)] = feW3[i]; }
    if (t >= 224 && t < 233) sb2[t - 224] = feb2[t - 224];
    if (t >= 240 && t < 249) sb3[t - 240] = feb3[t - 240];
    __syncthreads();

    const int idx = idx0 + t;
    const bool valid = idx < fill;
    const int lane = t & 63;
    if (__ballot(valid) == 0ull) return;           // wave fully past fill

    int dl;
    float o[9];
    if (valid) {
        const unsigned pk = sed[b * SLOT + idx];
        dl = (int)(pk >> 17);
        const int s = (int)(pk & 0x1FFFFu);

        // h1 = relu(base1[d] + base_s[s]); consecutive lanes share d -> L1 hits
        float a[9];
        {
            const float4* pb = reinterpret_cast<const float4*>(base1 + (size_t)(b * 128 + dl) * 12);
            float4 b0 = pb[0], b1 = pb[1];
            const float b8 = base1[(size_t)(b * 128 + dl) * 12 + 8];
            const float4* ps = reinterpret_cast<const float4*>(bases + (size_t)s * 16);
            float4 c0 = ps[0], c1 = ps[1];
            const float c8 = bases[(size_t)s * 16 + 8];
            a[0] = b0.x + c0.x; a[1] = b0.y + c0.y; a[2] = b0.z + c0.z; a[3] = b0.w + c0.w;
            a[4] = b1.x + c1.x; a[5] = b1.y + c1.y; a[6] = b1.z + c1.z; a[7] = b1.w + c1.w;
            a[8] = b8 + c8;
        }
        #pragma unroll
        for (int j = 0; j < 9; ++j) a[j] = fmaxf(a[j], 0.f);

        float h2[9];
        #pragma unroll
        for (int j = 0; j < 9; ++j) h2[j] = sb2[j];
        #pragma unroll
        for (int i = 0; i < 9; ++i) {
            const float ai = a[i];
            #pragma unroll
            for (int j = 0; j < 9; ++j) h2[j] = fmaf(ai, sW2[i * 12 + j], h2[j]);
        }
        #pragma unroll
        for (int j = 0; j < 9; ++j) h2[j] = fmaxf(h2[j], 0.f);

        #pragma unroll
        for (int j = 0; j < 9; ++j) o[j] = sb3[j];
        #pragma unroll
        for (int i = 0; i < 9; ++i) {
            const float hi = h2[i];
            #pragma unroll
            for (int j = 0; j < 9; ++j) o[j] = fmaf(hi, sW3[i * 12 + j], o[j]);
        }
    } else {
        dl = 128 + lane;                            // unique sentinel: own segment
        #pragma unroll
        for (int j = 0; j < 9; ++j) o[j] = 0.f;
    }

    // segmented inclusive scan by dl over the 64-lane wave (dl sorted, proven R3)
    const int dprev = __shfl_up(dl, 1);
    const bool head = (lane == 0) || (dprev != dl);
    const unsigned long long hm = __ballot(head);
    const int dist = __clzll((long long)(hm << (63 - lane)));  // 0 if head
    #pragma unroll
    for (int off = 1; off < 64; off <<= 1) {
        const bool ok = (dist >= off);
        #pragma unroll
        for (int j = 0; j < 9; ++j) {
            const float ov = __shfl_up(o[j], off);
            o[j] += ok ? ov : 0.f;
        }
    }
    const bool tail = (lane == 63) || (((hm >> (lane + 1)) & 1ull) != 0ull);
    if (tail && valid) {                            // segment tail -> global m
        float* mp = m + (size_t)(b * 128 + dl) * 9;
        #pragma unroll
        for (int j = 0; j < 9; ++j) atomicAdd(mp + j, o[j]);
    }
}

// ---------------- node round: fx MLP + zero m + next base1/base_s ----------------

__global__ __launch_bounds__(256) void node4_k(
    const float* __restrict__ Xin, float* __restrict__ m,
    const float* __restrict__ fxW1, const float* __restrict__ fxb1,
    const float* __restrict__ fxW2, const float* __restrict__ fxb2,
    const float* __restrict__ fxW3, const float* __restrict__ fxb3,
    const float* __restrict__ feW1, const float* __restrict__ feb1,
    float* __restrict__ Xout, float* __restrict__ base1out,
    float* __restrict__ basesout)
{
    __shared__ float sU1[25 * 12], sU2[9 * 12], sU3[9 * 16];
    __shared__ float sW1d[16 * 12], sW1s[16 * 12];
    __shared__ float sNB[34], sEB1[9];
    const int t = threadIdx.x;
    if (t < 225) sU1[(t / 9) * 12 + (t % 9)] = fxW1[t];
    if (t < 81)  sU2[(t / 9) * 12 + (t % 9)] = fxW2[t];
    if (t < 144) sU3[t] = fxW3[t];
    if (t < 144) sW1d[(t / 9) * 12 + (t % 9)] = feW1[t];
    if (t >= 112) { int i = t - 112; sW1s[(i / 9) * 12 + (i % 9)] = feW1[144 + i]; }
    if (t < 9) sNB[t] = fxb1[t];
    if (t >= 32 && t < 41) sNB[9 + (t - 32)] = fxb2[t - 32];
    if (t >= 64 && t < 80) sNB[18 + (t - 64)] = fxb3[t - 64];
    if (t >= 96 && t < 105) sEB1[t - 96] = feb1[t - 96];
    __syncthreads();

    const int n = blockIdx.x * 256 + t;
    if (n >= NN) return;

    float xr[16];
    {
        const float4* p = reinterpret_cast<const float4*>(Xin + (size_t)n * 16);
        #pragma unroll
        for (int q = 0; q < 4; ++q) {
            float4 v = p[q];
            xr[4*q] = v.x; xr[4*q+1] = v.y; xr[4*q+2] = v.z; xr[4*q+3] = v.w;
        }
    }
    float mm[9];
    float* mp = m + (size_t)n * 9;
    #pragma unroll
    for (int j = 0; j < 9; ++j) mm[j] = mp[j];
    #pragma unroll
    for (int j = 0; j < 9; ++j) mp[j] = 0.f;     // ready for next round

    float h1[9];
    #pragma unroll
    for (int j = 0; j < 9; ++j) h1[j] = sNB[j];
    #pragma unroll
    for (int i = 0; i < 16; ++i) {
        const float xi = xr[i];
        #pragma unroll
        for (int j = 0; j < 9; ++j) h1[j] = fmaf(xi, sU1[i * 12 + j], h1[j]);
    }
    #pragma unroll
    for (int i = 0; i < 9; ++i) {
        const float xi = mm[i];
        #pragma unroll
        for (int j = 0; j < 9; ++j) h1[j] = fmaf(xi, sU1[(16 + i) * 12 + j], h1[j]);
    }
    #pragma unroll
    for (int j = 0; j < 9; ++j) h1[j] = fmaxf(h1[j], 0.f);

    float h2[9];
    #pragma unroll
    for (int j = 0; j < 9; ++j) h2[j] = sNB[9 + j];
    #pragma unroll
    for (int i = 0; i < 9; ++i) {
        const float xi = h1[i];
        #pragma unroll
        for (int j = 0; j < 9; ++j) h2[j] = fmaf(xi, sU2[i * 12 + j], h2[j]);
    }
    #pragma unroll
    for (int j = 0; j < 9; ++j) h2[j] = fmaxf(h2[j], 0.f);

    float o[16];
    #pragma unroll
    for (int k = 0; k < 16; ++k) o[k] = sNB[18 + k];
    #pragma unroll
    for (int j = 0; j < 9; ++j) {
        const float hj = h2[j];
        #pragma unroll
        for (int k = 0; k < 16; ++k) o[k] = fmaf(hj, sU3[j * 16 + k], o[k]);
    }

    float4* po = reinterpret_cast<float4*>(Xout + (size_t)n * 16);
    #pragma unroll
    for (int q = 0; q < 4; ++q) {
        float4 v;
        v.x = o[4*q]; v.y = o[4*q+1]; v.z = o[4*q+2]; v.w = o[4*q+3];
        po[q] = v;
    }

    // base1 / base_s for NEXT round's edge kernel
    float bb[9];
    #pragma unroll
    for (int j = 0; j < 9; ++j) bb[j] = sEB1[j];
    #pragma unroll
    for (int i = 0; i < 16; ++i) {
        const float xi = o[i];
        #pragma unroll
        for (int j = 0; j < 9; ++j) bb[j] = fmaf(xi, sW1d[i * 12 + j], bb[j]);
    }
    float* bp = base1out + (size_t)n * 12;
    #pragma unroll
    for (int j = 0; j < 9; ++j) bp[j] = bb[j];

    float cc[9];
    #pragma unroll
    for (int j = 0; j < 9; ++j) cc[j] = 0.f;
    #pragma unroll
    for (int i = 0; i < 16; ++i) {
        const float xi = o[i];
        #pragma unroll
        for (int j = 0; j < 9; ++j) cc[j] = fmaf(xi, sW1s[i * 12 + j], cc[j]);
    }
    float* sp = basesout + (size_t)n * 16;
    #pragma unroll
    for (int j = 0; j < 9; ++j) sp[j] = cc[j];
}

extern "C" void kernel_launch(void* const* d_in, const int* in_sizes, int n_in,
                              void* d_out, int out_size, void* d_ws, size_t ws_size,
                              hipStream_t stream)
{
    (void)in_sizes; (void)n_in; (void)out_size; (void)ws_size;
    const float* X0   = (const float*)d_in[0];
    const int*   esrc = (const int*)d_in[1];
    const int*   edst = (const int*)d_in[2];
    const float* feW1 = (const float*)d_in[3];
    const float* feb1 = (const float*)d_in[4];
    const float* feW2 = (const float*)d_in[5];
    const float* feb2 = (const float*)d_in[6];
    const float* feW3 = (const float*)d_in[7];
    const float* feb3 = (const float*)d_in[8];
    const float* fxW1 = (const float*)d_in[9];
    const float* fxb1 = (const float*)d_in[10];
    const float* fxW2 = (const float*)d_in[11];
    const float* fxb2 = (const float*)d_in[12];
    const float* fxW3 = (const float*)d_in[13];
    const float* fxb3 = (const float*)d_in[14];
    float* out = (float*)d_out;

    // workspace layout (floats unless noted). total ~40 MB.
    float* base1  = (float*)d_ws;                         // NN*12 (stride 12)
    float* bases  = base1 + (size_t)NN * 12;              // NN*16 (64B rows)
    float* mb     = bases + (size_t)NN * 16;              // NN*9
    int* gcursor  = (int*)(mb + (size_t)NN * 9);          // NBK (padded to 1024)
    unsigned* sed = (unsigned*)(gcursor + 1024);          // NBK*SLOT u32 = 25.6MB

    const dim3 thr(256);
    const dim3 gS(NBLK_SORT);          // 782
    const dim3 gL(NBK);                // 782
    const dim3 gE(NBK * (SLOT / 256)); // 25024
    const dim3 gN(NB_NODE);            // 391

    // ---- two-level sort (once per launch) ----
    init_k<<<4, thr, 0, stream>>>(gcursor);
    bsort_k<<<gS, thr, 0, stream>>>(esrc, edst, gcursor, sed);
    lsort_k<<<gL, dim3(512), 0, stream>>>(sed, gcursor);

    // ---- round 0 ----
    base_k<<<gN, thr, 0, stream>>>(X0, feW1, feb1, base1, bases, mb);
    edge5_k<<<gE, thr, 0, stream>>>(base1, bases, sed, gcursor,
                                    feW2, feb2, feW3, feb3, mb);
    node4_k<<<gN, thr, 0, stream>>>(X0, mb, fxW1, fxb1, fxW2, fxb2, fxW3, fxb3,
                                    feW1, feb1, out, base1, bases);
    // ---- round 1 (node updates out in place; edge never reads X) ----
    edge5_k<<<gE, thr, 0, stream>>>(base1, bases, sed, gcursor,
                                    feW2, feb2, feW3, feb3, mb);
    node4_k<<<gN, thr, 0, stream>>>(out, mb, fxW1, fxb1, fxW2, fxb2, fxW3, fxb3,
                                    feW1, feb1, out, base1, bases);
    // ---- round 2 ----
    edge5_k<<<gE, thr, 0, stream>>>(base1, bases, sed, gcursor,
                                    feW2, feb2, feW3, feb3, mb);
    node4_k<<<gN, thr, 0, stream>>>(out, mb, fxW1, fxb1, fxW2, fxb2, fxW3, fxb3,
                                    feW1, feb1, out, base1, bases);
}